// Round 3
// baseline (232.496 us; speedup 1.0000x reference)
//
#include <hip/hip_runtime.h>
#include <hip/hip_bf16.h>

#define BT     16
#define C_IN   32
#define C_OUT  32
#define NRAND  16
#define NNODES 32768   // 32*32*32

typedef __attribute__((ext_vector_type(8))) short bf16x8;   // 8 bf16 = 4 VGPRs
typedef __attribute__((ext_vector_type(4))) float f32x4;

__device__ inline unsigned short f2bf(float f) {
    __hip_bfloat16 h = __float2bfloat16(f);
    return __builtin_bit_cast(unsigned short, h);
}

// ---------------------------------------------------------------------------
// x (b,c,m) fp32  ->  xT (b,m,c) bf16.   One node-vector = 32 bf16 = 64 B.
// ---------------------------------------------------------------------------
__global__ __launch_bounds__(256) void build_xt_bf16(
    const float* __restrict__ x, unsigned short* __restrict__ xT) {
    __shared__ float tile[C_IN][65];          // +1 pad: conflict-free col reads
    const int b     = blockIdx.y;
    const int mbase = blockIdx.x * 64;
    const int tid   = threadIdx.x;

    #pragma unroll
    for (int i = 0; i < 2; ++i) {             // 512 float4 reads
        int lin = tid + i * 256;
        int c   = lin >> 4;                   // 0..31
        int mg  = lin & 15;                   // 0..15 (x4 nodes)
        float4 v = *reinterpret_cast<const float4*>(
            &x[((size_t)b * C_IN + c) * NNODES + mbase + mg * 4]);
        tile[c][mg * 4 + 0] = v.x;
        tile[c][mg * 4 + 1] = v.y;
        tile[c][mg * 4 + 2] = v.z;
        tile[c][mg * 4 + 3] = v.w;
    }
    __syncthreads();
    #pragma unroll
    for (int i = 0; i < 2; ++i) {             // 512 ushort4 writes (8 B, c-contig)
        int lin = tid + i * 256;
        int m0  = lin >> 3;                   // 0..63
        int cg  = lin & 7;                    // 0..7 (x4 channels)
        ushort4 u;
        u.x = f2bf(tile[cg * 4 + 0][m0]);
        u.y = f2bf(tile[cg * 4 + 1][m0]);
        u.z = f2bf(tile[cg * 4 + 2][m0]);
        u.w = f2bf(tile[cg * 4 + 3][m0]);
        *reinterpret_cast<ushort4*>(
            &xT[(((size_t)b << 15) + mbase + m0) * C_IN + cg * 4]) = u;
    }
}

// ---------------------------------------------------------------------------
// W (o,c,r) fp32 -> Wp bf16 in MFMA A-frag order:
//   Wp[(((h*16 + r)*4 + g)*16 + row)*8 + e] = W[o=h*16+row][c=g*8+e][r]
// ---------------------------------------------------------------------------
__global__ __launch_bounds__(256) void build_w_bf16(
    const float* __restrict__ w, unsigned short* __restrict__ Wp) {
    int i = blockIdx.x * 256 + threadIdx.x;   // 16384
    int e   = i & 7;
    int row = (i >> 3) & 15;
    int g   = (i >> 7) & 3;
    int r   = (i >> 9) & 15;
    int h   = i >> 13;
    int o = h * 16 + row;
    int c = g * 8 + e;
    Wp[i] = f2bf(w[((size_t)o * C_IN + c) * NRAND + r]);
}

// ---------------------------------------------------------------------------
// Main MFMA kernel, 2-stage software pipeline at 8-gather granularity.
// Block = 256 thr = 4 waves; each wave: 4 tiles of (32 o x 16 n), K = 512.
// While MFMA-ing r-half A, half B's gathers + next tile's idx are in flight.
// ---------------------------------------------------------------------------
__global__ __launch_bounds__(256, 4) void mixer_mfma(
    const unsigned short* __restrict__ xT,
    const unsigned short* __restrict__ Wp,
    const float* __restrict__ bias,
    const int*   __restrict__ idx,
    float*       __restrict__ out) {
    __shared__ unsigned short wlds[2 * NRAND * 4 * 16 * 8];   // 32 KiB

    // blockIdx -> (xcd, batch, chunk): each XCD runs its 2 batches SEQUENTIALLY
    const int bid   = blockIdx.x;             // 0..2047
    const int xcd   = bid & 7;
    const int jj    = bid >> 3;               // 0..255
    const int b     = xcd * 2 + (jj >> 7);
    const int chunk = jj & 127;

    const int wave  = threadIdx.x >> 6;
    const int lane  = threadIdx.x & 63;
    const int row   = lane & 15;              // n-offset within tile / A-row
    const int g     = lane >> 4;              // lane-group: c-chunk g*8..g*8+7
    const int goff  = g << 3;
    const int nbase = chunk * 256 + wave * 64;

    const unsigned short* xb = xT + ((size_t)b << 20);        // b*32768*32

    // ---- prologue: tile-0 idx + half-0 gathers, overlapped with LDS fill ----
    const int4* ip0 = reinterpret_cast<const int4*>(idx) + (size_t)(nbase + row) * 4;
    int4 ipA0 = ip0[0], ipA1 = ip0[1], ipA2 = ip0[2], ipA3 = ip0[3];

    {
        const uint4* src = reinterpret_cast<const uint4*>(Wp);
        uint4*       dst = reinterpret_cast<uint4*>(wlds);
        #pragma unroll
        for (int i = 0; i < 8; ++i)
            dst[threadIdx.x + i * 256] = src[threadIdx.x + i * 256];
    }

    #define GATHER4(d0, d1, d2, d3, iv)                                             \
        d0 = *reinterpret_cast<const bf16x8*>(xb + (((size_t)(iv).x) << 5) + goff); \
        d1 = *reinterpret_cast<const bf16x8*>(xb + (((size_t)(iv).y) << 5) + goff); \
        d2 = *reinterpret_cast<const bf16x8*>(xb + (((size_t)(iv).z) << 5) + goff); \
        d3 = *reinterpret_cast<const bf16x8*>(xb + (((size_t)(iv).w) << 5) + goff)

    bf16x8 bufA[8];
    GATHER4(bufA[0], bufA[1], bufA[2], bufA[3], ipA0);
    GATHER4(bufA[4], bufA[5], bufA[6], bufA[7], ipA1);

    __syncthreads();

    const bf16x8* wfrag = reinterpret_cast<const bf16x8*>(wlds);
    const float4  bv0   = reinterpret_cast<const float4*>(bias)[g];
    const float4  bv1   = reinterpret_cast<const float4*>(bias)[g + 4];

    #pragma unroll 1
    for (int t = 0; t < 4; ++t) {
        // (a) prefetch next tile's idx rows (one full MFMA phase of slack)
        int4 ipB0, ipB1, ipB2, ipB3;
        if (t < 3) {
            const int4* ipn = reinterpret_cast<const int4*>(idx)
                              + (size_t)(nbase + (t + 1) * 16 + row) * 4;
            ipB0 = ipn[0]; ipB1 = ipn[1]; ipB2 = ipn[2]; ipB3 = ipn[3];
        }

        // (b) issue half-1 gathers for current tile
        bf16x8 bufB[8];
        GATHER4(bufB[0], bufB[1], bufB[2], bufB[3], ipA2);
        GATHER4(bufB[4], bufB[5], bufB[6], bufB[7], ipA3);

        f32x4 c0 = {bv0.x, bv0.y, bv0.z, bv0.w};
        f32x4 c1 = {bv1.x, bv1.y, bv1.z, bv1.w};

        // (c) MFMA half-0 (r = 0..7) on bufA — bufB/ipB in flight underneath
        #pragma unroll
        for (int r = 0; r < 8; ++r) {
            c0 = __builtin_amdgcn_mfma_f32_16x16x32_bf16(
                     wfrag[(r * 4 + g) * 16 + row], bufA[r], c0, 0, 0, 0);
            c1 = __builtin_amdgcn_mfma_f32_16x16x32_bf16(
                     wfrag[((NRAND + r) * 4 + g) * 16 + row], bufA[r], c1, 0, 0, 0);
        }

        // (d) issue next tile's half-0 gathers into bufA
        if (t < 3) {
            GATHER4(bufA[0], bufA[1], bufA[2], bufA[3], ipB0);
            GATHER4(bufA[4], bufA[5], bufA[6], bufA[7], ipB1);
        }

        // (e) MFMA half-1 (r = 8..15) on bufB — bufA' in flight underneath
        #pragma unroll
        for (int r = 8; r < 16; ++r) {
            c0 = __builtin_amdgcn_mfma_f32_16x16x32_bf16(
                     wfrag[(r * 4 + g) * 16 + row], bufB[r - 8], c0, 0, 0, 0);
            c1 = __builtin_amdgcn_mfma_f32_16x16x32_bf16(
                     wfrag[((NRAND + r) * 4 + g) * 16 + row], bufB[r - 8], c1, 0, 0, 0);
        }

        // (f) store tile: C/D layout col = lane&15 -> n, row = g*4+reg -> o
        float* ob = out + (((size_t)b * C_OUT) << 15) + nbase + t * 16 + row;
        #pragma unroll
        for (int jr = 0; jr < 4; ++jr) {
            __builtin_nontemporal_store(c0[jr], ob + (((size_t)(g * 4 + jr)) << 15));
            __builtin_nontemporal_store(c1[jr], ob + (((size_t)(g * 4 + jr + 16)) << 15));
        }

        ipA0 = ipB0; ipA1 = ipB1; ipA2 = ipB2; ipA3 = ipB3;
    }
    #undef GATHER4
}

// ---------------------------------------------------------------------------
// fp32 fallback (ws too small) — round-0 kernel, known-correct.
// ---------------------------------------------------------------------------
__global__ __launch_bounds__(256) void mixer_fallback(
    const float* __restrict__ xsrc, const float* __restrict__ wsrc,
    const float* __restrict__ bias, const int* __restrict__ idx,
    float* __restrict__ out) {
    const int b = blockIdx.y;
    const int n = blockIdx.x * 256 + threadIdx.x;
    float acc[C_OUT];
    #pragma unroll
    for (int o = 0; o < C_OUT; ++o) acc[o] = bias[o];
    #pragma unroll 1
    for (int r = 0; r < NRAND; ++r) {
        const int m = idx[(size_t)n * NRAND + r];
        #pragma unroll
        for (int c = 0; c < C_IN; ++c) {
            const float xs = xsrc[((size_t)b * C_IN + c) * NNODES + m];
            #pragma unroll
            for (int o = 0; o < C_OUT; ++o)
                acc[o] += wsrc[((size_t)o * C_IN + c) * NRAND + r] * xs;
        }
    }
    #pragma unroll
    for (int o = 0; o < C_OUT; ++o)
        out[((size_t)b * C_OUT + o) * NNODES + n] = acc[o];
}

// ---------------------------------------------------------------------------
extern "C" void kernel_launch(void* const* d_in, const int* in_sizes, int n_in,
                              void* d_out, int out_size, void* d_ws, size_t ws_size,
                              hipStream_t stream) {
    const float* x    = (const float*)d_in[0];
    const float* w    = (const float*)d_in[1];
    const float* bias = (const float*)d_in[2];
    const int*   idx  = (const int*)d_in[3];
    float*       out  = (float*)d_out;

    const size_t xT_bytes = (size_t)BT * NNODES * C_IN * sizeof(unsigned short); // 32 MiB
    const size_t wp_bytes = (size_t)2 * NRAND * 4 * 16 * 8 * sizeof(unsigned short); // 32 KiB

    if (ws_size >= xT_bytes + wp_bytes) {
        unsigned short* xT = (unsigned short*)d_ws;
        unsigned short* Wp = (unsigned short*)((char*)d_ws + xT_bytes);

        dim3 tg(NNODES / 64, BT);
        build_xt_bf16<<<tg, 256, 0, stream>>>(x, xT);
        build_w_bf16<<<(2 * NRAND * 4 * 16 * 8) / 256, 256, 0, stream>>>(w, Wp);

        mixer_mfma<<<BT * (NNODES / 256), 256, 0, stream>>>(xT, Wp, bias, idx, out);
    } else {
        dim3 g(NNODES / 256, BT);
        mixer_fallback<<<g, 256, 0, stream>>>(x, w, bias, idx, out);
    }
}

// Round 4
// 78.519 us; speedup vs baseline: 2.9610x; 2.9610x over previous
//
#include <hip/hip_runtime.h>
#include <hip/hip_bf16.h>

#define BT     16
#define C_IN   32
#define C_OUT  32
#define NRAND  16
#define NNODES 32768   // 32*32*32

typedef __attribute__((ext_vector_type(8))) short bf16x8;   // 8 bf16 = 4 VGPRs
typedef __attribute__((ext_vector_type(4))) float f32x4;

__device__ inline unsigned short f2bf(float f) {
    __hip_bfloat16 h = __float2bfloat16(f);
    return __builtin_bit_cast(unsigned short, h);
}

// ---------------------------------------------------------------------------
// x (b,c,m) fp32  ->  xT (b,m,c) bf16.   One node-vector = 32 bf16 = 64 B.
// ---------------------------------------------------------------------------
__global__ __launch_bounds__(256) void build_xt_bf16(
    const float* __restrict__ x, unsigned short* __restrict__ xT) {
    __shared__ float tile[C_IN][65];          // +1 pad: conflict-free col reads
    const int b     = blockIdx.y;
    const int mbase = blockIdx.x * 64;
    const int tid   = threadIdx.x;

    #pragma unroll
    for (int i = 0; i < 2; ++i) {             // 512 float4 reads
        int lin = tid + i * 256;
        int c   = lin >> 4;                   // 0..31
        int mg  = lin & 15;                   // 0..15 (x4 nodes)
        float4 v = *reinterpret_cast<const float4*>(
            &x[((size_t)b * C_IN + c) * NNODES + mbase + mg * 4]);
        tile[c][mg * 4 + 0] = v.x;
        tile[c][mg * 4 + 1] = v.y;
        tile[c][mg * 4 + 2] = v.z;
        tile[c][mg * 4 + 3] = v.w;
    }
    __syncthreads();
    #pragma unroll
    for (int i = 0; i < 2; ++i) {             // 512 ushort4 writes (8 B, c-contig)
        int lin = tid + i * 256;
        int m0  = lin >> 3;                   // 0..63
        int cg  = lin & 7;                    // 0..7 (x4 channels)
        ushort4 u;
        u.x = f2bf(tile[cg * 4 + 0][m0]);
        u.y = f2bf(tile[cg * 4 + 1][m0]);
        u.z = f2bf(tile[cg * 4 + 2][m0]);
        u.w = f2bf(tile[cg * 4 + 3][m0]);
        *reinterpret_cast<ushort4*>(
            &xT[(((size_t)b << 15) + mbase + m0) * C_IN + cg * 4]) = u;
    }
}

// ---------------------------------------------------------------------------
// W (o,c,r) fp32 -> Wp bf16 in MFMA A-frag order:
//   Wp[(((h*16 + r)*4 + g)*16 + row)*8 + e] = W[o=h*16+row][c=g*8+e][r]
// ---------------------------------------------------------------------------
__global__ __launch_bounds__(256) void build_w_bf16(
    const float* __restrict__ w, unsigned short* __restrict__ Wp) {
    int i = blockIdx.x * 256 + threadIdx.x;   // 16384
    int e   = i & 7;
    int row = (i >> 3) & 15;
    int g   = (i >> 7) & 3;
    int r   = (i >> 9) & 15;
    int h   = i >> 13;
    int o = h * 16 + row;
    int c = g * 8 + e;
    Wp[i] = f2bf(w[((size_t)o * C_IN + c) * NRAND + r]);
}

// ---------------------------------------------------------------------------
// Main MFMA kernel, 2-stage software pipeline at 8-gather granularity.
// Block = 256 thr = 4 waves; each wave: 4 tiles of (32 o x 16 n), K = 512.
// NO min-waves launch bound: R2 showed (256,4) caps VGPR at 64 -> the two
// 8-frag buffers spill to scratch (FETCH 33->614 MB, 3x regression). Let the
// allocator take ~160 VGPR; 3 waves/SIMD of TLP + in-wave ILP hides L2.
// ---------------------------------------------------------------------------
__global__ __launch_bounds__(256) void mixer_mfma(
    const unsigned short* __restrict__ xT,
    const unsigned short* __restrict__ Wp,
    const float* __restrict__ bias,
    const int*   __restrict__ idx,
    float*       __restrict__ out) {
    __shared__ unsigned short wlds[2 * NRAND * 4 * 16 * 8];   // 32 KiB

    // blockIdx -> (xcd, batch, chunk): each XCD runs its 2 batches SEQUENTIALLY
    const int bid   = blockIdx.x;             // 0..2047
    const int xcd   = bid & 7;
    const int jj    = bid >> 3;               // 0..255
    const int b     = xcd * 2 + (jj >> 7);
    const int chunk = jj & 127;

    const int wave  = threadIdx.x >> 6;
    const int lane  = threadIdx.x & 63;
    const int row   = lane & 15;              // n-offset within tile / A-row
    const int g     = lane >> 4;              // lane-group: c-chunk g*8..g*8+7
    const int goff  = g << 3;
    const int nbase = chunk * 256 + wave * 64;

    const unsigned short* xb = xT + ((size_t)b << 20);        // b*32768*32

    // ---- prologue: tile-0 idx + half-0 gathers, overlapped with LDS fill ----
    const int4* ip0 = reinterpret_cast<const int4*>(idx) + (size_t)(nbase + row) * 4;
    int4 ipA0 = ip0[0], ipA1 = ip0[1], ipA2 = ip0[2], ipA3 = ip0[3];

    {
        const uint4* src = reinterpret_cast<const uint4*>(Wp);
        uint4*       dst = reinterpret_cast<uint4*>(wlds);
        #pragma unroll
        for (int i = 0; i < 8; ++i)
            dst[threadIdx.x + i * 256] = src[threadIdx.x + i * 256];
    }

    #define GATHER4(d0, d1, d2, d3, iv)                                             \
        d0 = *reinterpret_cast<const bf16x8*>(xb + (((size_t)(iv).x) << 5) + goff); \
        d1 = *reinterpret_cast<const bf16x8*>(xb + (((size_t)(iv).y) << 5) + goff); \
        d2 = *reinterpret_cast<const bf16x8*>(xb + (((size_t)(iv).z) << 5) + goff); \
        d3 = *reinterpret_cast<const bf16x8*>(xb + (((size_t)(iv).w) << 5) + goff)

    bf16x8 bufA[8];
    GATHER4(bufA[0], bufA[1], bufA[2], bufA[3], ipA0);
    GATHER4(bufA[4], bufA[5], bufA[6], bufA[7], ipA1);

    __syncthreads();

    const bf16x8* wfrag = reinterpret_cast<const bf16x8*>(wlds);
    const float4  bv0   = reinterpret_cast<const float4*>(bias)[g];
    const float4  bv1   = reinterpret_cast<const float4*>(bias)[g + 4];

    #pragma unroll 1
    for (int t = 0; t < 4; ++t) {
        // (a) prefetch next tile's idx rows (one full MFMA phase of slack)
        int4 ipB0, ipB1, ipB2, ipB3;
        if (t < 3) {
            const int4* ipn = reinterpret_cast<const int4*>(idx)
                              + (size_t)(nbase + (t + 1) * 16 + row) * 4;
            ipB0 = ipn[0]; ipB1 = ipn[1]; ipB2 = ipn[2]; ipB3 = ipn[3];
        }

        // (b) issue half-1 gathers for current tile
        bf16x8 bufB[8];
        GATHER4(bufB[0], bufB[1], bufB[2], bufB[3], ipA2);
        GATHER4(bufB[4], bufB[5], bufB[6], bufB[7], ipA3);

        f32x4 c0 = {bv0.x, bv0.y, bv0.z, bv0.w};
        f32x4 c1 = {bv1.x, bv1.y, bv1.z, bv1.w};

        // (c) MFMA half-0 (r = 0..7) on bufA — bufB/ipB in flight underneath
        #pragma unroll
        for (int r = 0; r < 8; ++r) {
            c0 = __builtin_amdgcn_mfma_f32_16x16x32_bf16(
                     wfrag[(r * 4 + g) * 16 + row], bufA[r], c0, 0, 0, 0);
            c1 = __builtin_amdgcn_mfma_f32_16x16x32_bf16(
                     wfrag[((NRAND + r) * 4 + g) * 16 + row], bufA[r], c1, 0, 0, 0);
        }

        // (d) issue next tile's half-0 gathers into bufA
        if (t < 3) {
            GATHER4(bufA[0], bufA[1], bufA[2], bufA[3], ipB0);
            GATHER4(bufA[4], bufA[5], bufA[6], bufA[7], ipB1);
        }

        // (e) MFMA half-1 (r = 8..15) on bufB — bufA' in flight underneath
        #pragma unroll
        for (int r = 8; r < 16; ++r) {
            c0 = __builtin_amdgcn_mfma_f32_16x16x32_bf16(
                     wfrag[(r * 4 + g) * 16 + row], bufB[r - 8], c0, 0, 0, 0);
            c1 = __builtin_amdgcn_mfma_f32_16x16x32_bf16(
                     wfrag[((NRAND + r) * 4 + g) * 16 + row], bufB[r - 8], c1, 0, 0, 0);
        }

        // (f) store tile: C/D layout col = lane&15 -> n, row = g*4+reg -> o
        float* ob = out + (((size_t)b * C_OUT) << 15) + nbase + t * 16 + row;
        #pragma unroll
        for (int jr = 0; jr < 4; ++jr) {
            __builtin_nontemporal_store(c0[jr], ob + (((size_t)(g * 4 + jr)) << 15));
            __builtin_nontemporal_store(c1[jr], ob + (((size_t)(g * 4 + jr + 16)) << 15));
        }

        ipA0 = ipB0; ipA1 = ipB1; ipA2 = ipB2; ipA3 = ipB3;
    }
    #undef GATHER4
}

// ---------------------------------------------------------------------------
// fp32 fallback (ws too small) — round-0 kernel, known-correct.
// ---------------------------------------------------------------------------
__global__ __launch_bounds__(256) void mixer_fallback(
    const float* __restrict__ xsrc, const float* __restrict__ wsrc,
    const float* __restrict__ bias, const int* __restrict__ idx,
    float* __restrict__ out) {
    const int b = blockIdx.y;
    const int n = blockIdx.x * 256 + threadIdx.x;
    float acc[C_OUT];
    #pragma unroll
    for (int o = 0; o < C_OUT; ++o) acc[o] = bias[o];
    #pragma unroll 1
    for (int r = 0; r < NRAND; ++r) {
        const int m = idx[(size_t)n * NRAND + r];
        #pragma unroll
        for (int c = 0; c < C_IN; ++c) {
            const float xs = xsrc[((size_t)b * C_IN + c) * NNODES + m];
            #pragma unroll
            for (int o = 0; o < C_OUT; ++o)
                acc[o] += wsrc[((size_t)o * C_IN + c) * NRAND + r] * xs;
        }
    }
    #pragma unroll
    for (int o = 0; o < C_OUT; ++o)
        out[((size_t)b * C_OUT + o) * NNODES + n] = acc[o];
}

// ---------------------------------------------------------------------------
extern "C" void kernel_launch(void* const* d_in, const int* in_sizes, int n_in,
                              void* d_out, int out_size, void* d_ws, size_t ws_size,
                              hipStream_t stream) {
    const float* x    = (const float*)d_in[0];
    const float* w    = (const float*)d_in[1];
    const float* bias = (const float*)d_in[2];
    const int*   idx  = (const int*)d_in[3];
    float*       out  = (float*)d_out;

    const size_t xT_bytes = (size_t)BT * NNODES * C_IN * sizeof(unsigned short); // 32 MiB
    const size_t wp_bytes = (size_t)2 * NRAND * 4 * 16 * 8 * sizeof(unsigned short); // 32 KiB

    if (ws_size >= xT_bytes + wp_bytes) {
        unsigned short* xT = (unsigned short*)d_ws;
        unsigned short* Wp = (unsigned short*)((char*)d_ws + xT_bytes);

        dim3 tg(NNODES / 64, BT);
        build_xt_bf16<<<tg, 256, 0, stream>>>(x, xT);
        build_w_bf16<<<(2 * NRAND * 4 * 16 * 8) / 256, 256, 0, stream>>>(w, Wp);

        mixer_mfma<<<BT * (NNODES / 256), 256, 0, stream>>>(xT, Wp, bias, idx, out);
    } else {
        dim3 g(NNODES / 256, BT);
        mixer_fallback<<<g, 256, 0, stream>>>(x, w, bias, idx, out);
    }
}